// Round 8
// baseline (16.719 us; speedup 1.0000x reference)
//
#include <hip/hip_runtime.h>
#include <hip/hip_bf16.h>
#include <string.h>

// TaylorLayer via MFMA: out[B,8] = relu(W[8,164] @ epd[164,B] + b), B=262144.
// epd = monomials deg 1..3 of x[8], reference recursion order, T=164.
//
// Measured (R6): true kernel ~5.8us (R7), fixed harness overhead ~10.5us.
// Kernel time ~= C(4.5us: 2.7 HBM + latency/drain) + VALU_issue. R7's sigma
// restructure bought exactly its VALU model (-1.0us).
//
// R8: scheduling/VALU cleanup:
//  - sigma absorbed into load addressing: lane loads x+elem*8+4h and
//    x+elem*8+4(1-h) -> xs needs ZERO cndmask (R7 had 8 + select in chain).
//  - all sched_barrier(0) removed (their pressure rationale was disproved
//    by R6); compiler free to hoist af-stream loads / interleave MFMA.
//  - bias load after MFMA chain.
//
// MFMA mfma_f32_32x32x16_bf16, K=176. A: row=lane&31 (rows 8..31 zero),
// half h=lane>>5, slot 8i+j (prep_w, sigma-permuted W via TDX tables).
// B: col=lane&31, same k-map. C/D: col=lane&31, row=(reg&3)+8*(reg>>2)
// +4*(lane>>5) -> regs 0..3 = rows 4h+0..3 -> one float4 store.

static constexpr int TEXP = 164;
static constexpr int NOUT = 8;
static constexpr int NMFMA = 11;   // K = 176
static constexpr int NSLOT = 88;   // slots per k-half

using f32x16 = __attribute__((ext_vector_type(16))) float;
using short8 = __attribute__((ext_vector_type(8))) short;

// ---- reference t-order index math ----
constexpr int rowstart2(int j) { return j * 8 - j * (j - 1) / 2; }
constexpr int start3(int j) {
  int s = 44;
  for (int jp = 0; jp < j; ++jp) s += (8 - jp) * (9 - jp) / 2;
  return s;
}
constexpr int t3_of(int a, int b, int c) {
  int x = a, y = b, z = c, t = 0;
  if (x > y) { t = x; x = y; y = t; }
  if (y > z) { t = y; y = z; z = t; }
  if (x > y) { t = x; x = y; y = t; }
  int off = 0;
  for (int ap = x; ap < y; ++ap) off += 8 - ap;
  return start3(x) + off + (z - y);
}

// ---- slot table: 88 half-0 representatives (>=2 low indices) ----
struct Slot { int deg, a, b, c; };
struct SlotTable { Slot s[NSLOT]; };

constexpr bool isrep2(int j, int k) {      // j<=k
  if (k < 4) return true;
  if (j >= 4) return false;
  if (k == j + 4) return true;             // fixed (dup; W zero in half1)
  return j < k - 4;
}
constexpr bool isrep3(int a, int b, int c) {
  return ((a < 4) + (b < 4) + (c < 4)) >= 2;
}

constexpr SlotTable make_slots() {
  SlotTable T{};
  int s = 0;
  for (int j = 0; j < 4; ++j) T.s[s++] = {1, j, 0, 0};                 // 4
  for (int j = 0; j < 8; ++j)
    for (int k = j; k < 8; ++k)
      if (isrep2(j, k)) T.s[s++] = {2, j, k, 0};                       // 20
  for (int a = 0; a < 8; ++a)
    for (int b = a; b < 8; ++b)
      for (int c = b; c < 8; ++c)
        if (isrep3(a, b, c)) T.s[s++] = {3, a, b, c};                  // 60
  for (; s < NSLOT; ++s) T.s[s] = {0, 0, 0, 0};                        // 4 pads
  return T;
}
constexpr SlotTable SLOTS = make_slots();

// ---- per-(half,slot) -> reference t index (or -1 => W = 0) ----
struct TT { short t[2][NSLOT]; };
constexpr TT make_tt() {
  TT r{};
  for (int h = 0; h < 2; ++h)
    for (int s = 0; s < NSLOT; ++s) {
      Slot sl = SLOTS.s[s];
      int m = h ? 4 : 0;
      if (sl.deg == 0) { r.t[h][s] = -1; }
      else if (sl.deg == 1) { r.t[h][s] = (short)(sl.a ^ m); }
      else if (sl.deg == 2) {
        if (h == 1 && sl.b == (sl.a ^ 4)) { r.t[h][s] = -1; }
        else {
          int a = sl.a ^ m, b = sl.b ^ m;
          int lo = a < b ? a : b, hi2 = a < b ? b : a;
          r.t[h][s] = (short)(8 + rowstart2(lo) + (hi2 - lo));
        }
      } else {
        r.t[h][s] = (short)t3_of(sl.a ^ m, sl.b ^ m, sl.c ^ m);
      }
    }
  return r;
}
__device__ const TT TDX = make_tt();

__device__ __forceinline__ short bf16bits(float v) {
  __hip_bfloat16 h = __float2bfloat16(v);
  short s;
  memcpy(&s, &h, 2);
  return s;
}

// slot value from sigma-permuted inputs xs and d2 over xs (rows j<4)
template <int S>
__device__ __forceinline__ float slotval(const float (&xs)[8], const float (&d2)[36]) {
  constexpr int deg = SLOTS.s[S].deg;
  constexpr int a = SLOTS.s[S].a;
  constexpr int b = SLOTS.s[S].b;
  constexpr int c = SLOTS.s[S].c;
  if constexpr (deg == 1) return xs[a];
  else if constexpr (deg == 2) return d2[rowstart2(a) + (b - a)];        // a < 4
  else if constexpr (deg == 3) return xs[a] * d2[rowstart2(b) + (c - b)]; // b < 4
  else return 0.0f;
}

template <int I>
struct MfmaStep {
  static __device__ __forceinline__ void run(const float (&xs)[8], const float (&d2)[36],
                                             const unsigned short* __restrict__ wpl,
                                             short8 af_cur, f32x16& acc) {
    short8 af_next;
    if constexpr (I + 1 < NMFMA)
      af_next = *reinterpret_cast<const short8*>(wpl + (I + 1) * 64 * 8);
    short8 bv;
    bv[0] = bf16bits(slotval<8 * I + 0>(xs, d2));
    bv[1] = bf16bits(slotval<8 * I + 1>(xs, d2));
    bv[2] = bf16bits(slotval<8 * I + 2>(xs, d2));
    bv[3] = bf16bits(slotval<8 * I + 3>(xs, d2));
    bv[4] = bf16bits(slotval<8 * I + 4>(xs, d2));
    bv[5] = bf16bits(slotval<8 * I + 5>(xs, d2));
    bv[6] = bf16bits(slotval<8 * I + 6>(xs, d2));
    bv[7] = bf16bits(slotval<8 * I + 7>(xs, d2));
    acc = __builtin_amdgcn_mfma_f32_32x32x16_bf16(af_cur, bv, acc, 0, 0, 0);
    if constexpr (I + 1 < NMFMA)
      MfmaStep<I + 1>::run(xs, d2, wpl, af_next, acc);
  }
};

// ---- prep: wp[(i*64+lane)*8 + j] = bf16(W[row][ TDX[h][8i+j] ]) ----
__global__ void prep_w(const float* __restrict__ W, unsigned short* __restrict__ wp) {
  int idx = threadIdx.x + blockIdx.x * blockDim.x;
  if (idx >= NMFMA * 64 * 8) return;
  int j = idx & 7;
  int lane = (idx >> 3) & 63;
  int i = idx >> 9;
  int row = lane & 31, h = lane >> 5;
  int t = TDX.t[h][8 * i + j];
  float v = (row < NOUT && t >= 0) ? W[row * TEXP + t] : 0.0f;
  union { float f; unsigned int u; } c; c.f = v;
  unsigned int u = c.u;
  wp[idx] = (unsigned short)((u + 0x7fffu + ((u >> 16) & 1u)) >> 16);  // RNE
}

__global__ __launch_bounds__(256, 4) void taylor_mfma(
    const float* __restrict__ x, const float* __restrict__ b,
    const unsigned short* __restrict__ wp, float* __restrict__ out, int ngroups) {
  const int lane = (int)(threadIdx.x & 63);
  const int h = (lane >= 32) ? 1 : 0;
  const int col = lane & 31;

  const int g = (int)((blockIdx.x * blockDim.x + threadIdx.x) >> 6);
  if (g >= ngroups) return;
  const int elem = g * 32 + col;

  // sigma absorbed into addressing: xs[0..3] = x[elem][4h..], xs[4..7] =
  // x[elem][4(1-h)..]  (h=0: identity; h=1: j^4 permutation). No cndmask.
  const float* xe = x + elem * 8;
  float4 fA = *reinterpret_cast<const float4*>(xe + 4 * h);
  float4 fB = *reinterpret_cast<const float4*>(xe + 4 - 4 * h);
  float xs[8] = {fA.x, fA.y, fA.z, fA.w, fB.x, fB.y, fB.z, fB.w};

  const unsigned short* wpl = wp + lane * 8;
  short8 af0 = *reinterpret_cast<const short8*>(wpl);

  // d2 over xs, rows j<4 only (all slot reps have a low pair-lead)
  float d2[36];
#pragma unroll
  for (int j = 0; j < 4; ++j) {
#pragma unroll
    for (int k = j; k < 8; ++k) {
      d2[rowstart2(j) + (k - j)] = xs[j] * xs[k];
    }
  }

  f32x16 acc;
#pragma unroll
  for (int r = 0; r < 16; ++r) acc[r] = 0.0f;

  MfmaStep<0>::run(xs, d2, wpl, af0, acc);

  const float4 bv4 = *reinterpret_cast<const float4*>(b + 4 * h);
  float4 o;
  o.x = fmaxf(acc[0] + bv4.x, 0.0f);
  o.y = fmaxf(acc[1] + bv4.y, 0.0f);
  o.z = fmaxf(acc[2] + bv4.z, 0.0f);
  o.w = fmaxf(acc[3] + bv4.w, 0.0f);
  *reinterpret_cast<float4*>(out + elem * 8 + 4 * h) = o;
}

extern "C" void kernel_launch(void* const* d_in, const int* in_sizes, int n_in,
                              void* d_out, int out_size, void* d_ws, size_t ws_size,
                              hipStream_t stream) {
  const float* x = (const float*)d_in[0];   // [262144, 8, 1]
  const float* W = (const float*)d_in[1];   // [8, 164]
  const float* b = (const float*)d_in[2];   // [8, 1]
  float* out = (float*)d_out;               // [262144, 8]
  unsigned short* wp = (unsigned short*)d_ws;  // 11*64*8 bf16 = 11264 B

  int n = in_sizes[0] / 8;      // 262144 elements
  int ngroups = n / 32;         // 8192 wave-groups
  int blocks = ngroups / 4;     // 2048 blocks of 4 waves

  prep_w<<<22, 256, 0, stream>>>(W, wp);
  taylor_mfma<<<blocks, 256, 0, stream>>>(x, b, wp, out, ngroups);
}